// Round 4
// baseline (514.871 us; speedup 1.0000x reference)
//
#include <hip/hip_runtime.h>

#define NTOP 256

typedef __attribute__((ext_vector_type(8))) short bf16x8;
typedef __attribute__((ext_vector_type(4))) float f32x4;
typedef __attribute__((ext_vector_type(2))) float f32x2;

// round-to-nearest-even split of fp32 into bf16 hi/lo, packed (hi<<16)|lo
__device__ inline unsigned int packbf(float x) {
  unsigned int u = __float_as_uint(x);
  unsigned int r = (u + 0x7fffu + ((u >> 16) & 1u)) & 0xffff0000u;
  float res = x - __uint_as_float(r);
  unsigned int u2 = __float_as_uint(res);
  unsigned int r2 = u2 + 0x7fffu + ((u2 >> 16) & 1u);
  return r | (r2 >> 16);
}

__device__ inline float tanh_fast(float x) {
  float e = __expf(2.f * x);
  return 1.f - 2.f / (e + 1.f);
}

template <int CTRL>
__device__ inline float dpp_f(float v) {
  return __int_as_float(__builtin_amdgcn_update_dpp(
      0, __float_as_int(v), CTRL, 0xf, 0xf, true));
}

// inclusive prefix sum within each 16-lane row
__device__ inline float scan16(float v) {
  float s = v;
  s += dpp_f<0x111>(s);  // row_shr:1
  s += dpp_f<0x112>(s);  // row_shr:2
  s += dpp_f<0x114>(s);  // row_shr:4
  s += dpp_f<0x118>(s);  // row_shr:8
  return s;
}

// ---------------------------------------------------------------- K1
// R1 skeleton: 512 threads, 8 waves, j = tid>>1 (output), half = tid&1
// (k-half). Wc half-row in f32x2 regs -> v_pk_fma_f32 dual-issue; 4
// independent accumulator chains; 1 barrier/step; shfl_xor(1) reduce (DPP).
__global__ __launch_bounds__(512) void rsbc_recur(
    const float* __restrict__ Wih, const float* __restrict__ Whh,
    const float* __restrict__ bih, const float* __restrict__ bhh,
    const float* __restrict__ h0, unsigned int* __restrict__ Hpack) {
  __shared__ float hA[NTOP], hB[NTOP];
  const int tid = threadIdx.x;
  const int j = tid >> 1, half = tid & 1, k0 = half << 7;
  const float bj = bih[j] + bhh[j];

  f32x2 w[64];
  {
    const float4* wp = reinterpret_cast<const float4*>(Wih + j * NTOP + k0);
#pragma unroll
    for (int q = 0; q < 32; ++q) {
      float4 t = wp[q];
      w[2 * q]     = (f32x2){t.x, t.y};
      w[2 * q + 1] = (f32x2){t.z, t.w};
    }
  }
  if (tid < NTOP) hA[tid] = h0[tid];
  __syncthreads();

  // step 0: h1 = tanh(h0 @ Wih^T + b)
  {
    const float* hq = hA + k0;
    f32x2 a0 = {0.f, 0.f}, a1 = {0.f, 0.f}, a2 = {0.f, 0.f}, a3 = {0.f, 0.f};
#pragma unroll
    for (int q = 0; q < 16; ++q) {
      float4 u = *reinterpret_cast<const float4*>(hq + 8 * q);
      float4 v = *reinterpret_cast<const float4*>(hq + 8 * q + 4);
      a0 += (f32x2){u.x, u.y} * w[4 * q];
      a1 += (f32x2){u.z, u.w} * w[4 * q + 1];
      a2 += (f32x2){v.x, v.y} * w[4 * q + 2];
      a3 += (f32x2){v.z, v.w} * w[4 * q + 3];
    }
    f32x2 s2 = (a0 + a1) + (a2 + a3);
    float sv = s2.x + s2.y;
    sv += __shfl_xor(sv, 1);
    if (half == 0) {
      float v = tanh_fast(sv + bj);
      hB[j] = v;
      Hpack[j] = packbf(v);
    }
  }
  // Wc = W_ih + W_hh (global loads overlap step-0 tail)
  {
    const float4* wq = reinterpret_cast<const float4*>(Whh + j * NTOP + k0);
#pragma unroll
    for (int q = 0; q < 32; ++q) {
      float4 t = wq[q];
      w[2 * q]     += (f32x2){t.x, t.y};
      w[2 * q + 1] += (f32x2){t.z, t.w};
    }
  }
  __syncthreads();

#pragma unroll 1
  for (int s = 1; s < 255; ++s) {
    const float* hr = (s & 1) ? hB : hA;
    float* hw = (s & 1) ? hA : hB;
    const float* hq = hr + k0;
    f32x2 a0 = {0.f, 0.f}, a1 = {0.f, 0.f}, a2 = {0.f, 0.f}, a3 = {0.f, 0.f};
#pragma unroll
    for (int q = 0; q < 16; ++q) {
      float4 u = *reinterpret_cast<const float4*>(hq + 8 * q);
      float4 v = *reinterpret_cast<const float4*>(hq + 8 * q + 4);
      a0 += (f32x2){u.x, u.y} * w[4 * q];
      a1 += (f32x2){u.z, u.w} * w[4 * q + 1];
      a2 += (f32x2){v.x, v.y} * w[4 * q + 2];
      a3 += (f32x2){v.z, v.w} * w[4 * q + 3];
    }
    f32x2 s2 = (a0 + a1) + (a2 + a3);
    float sv = s2.x + s2.y;
    sv += __shfl_xor(sv, 1);
    if (half == 0) {
      float v = tanh_fast(sv + bj);
      hw[j] = v;
      Hpack[s * NTOP + j] = packbf(v);
    }
    __syncthreads();
  }
}

// ---------------------------------------------------------------- K2
// bf16x3 MFMA GEMM (Z @ H^T) + sigmoid + log-space stick-breaking.
// 512 threads (8 waves 2x4), BM=128, N=256, K-chunk=32 (8 chunks).
// LDS: A[128][hi|lo] 16KB + B[256][hi|lo] 32KB, XOR-swizzled. z prefetched
// one chunk ahead (8 VGPR only — H loaded in-phase, L2-hot). Register
// epilogue: softplus + DPP scan16 + rowT cross-wave fixup, direct store.
__global__ __launch_bounds__(512, 4) void rsbc_gemm_sb(
    const float* __restrict__ z, const unsigned int* __restrict__ Hpack,
    float* __restrict__ out) {
  __shared__ __align__(16) char smem[49152];
  __shared__ float rowT[128 * 5];
  char* Ab = smem;            // A plane: 128 rows x 128 B
  char* Bb = smem + 16384;    // B plane: 256 rows x 128 B

  const int tid = threadIdx.x;
  const size_t row0 = (size_t)blockIdx.x * 128;
  const int wid = tid >> 6, lane = tid & 63;
  const int wr = wid >> 2, wc = wid & 3;
  const int l15 = lane & 15, l4 = lane >> 4;

  f32x4 acc[4][4];
#pragma unroll
  for (int mt = 0; mt < 4; ++mt)
#pragma unroll
    for (int nt = 0; nt < 4; ++nt) acc[mt][nt] = (f32x4){0.f, 0.f, 0.f, 0.f};

  const int pr = tid >> 3, pq = tid & 7;       // staging decomposition
  // prefetch z chunk 0
  float4 zpre[2];
#pragma unroll
  for (int it = 0; it < 2; ++it) {
    int r = pr + 64 * it;
    zpre[it] = *reinterpret_cast<const float4*>(z + (row0 + r) * NTOP + 4 * pq);
  }

  for (int kc = 0; kc < 8; ++kc) {
    const int kb = kc * 32;
    __syncthreads();                  // prev chunk frag reads done
    // ---- A: convert prefetched z, swizzled LDS write
#pragma unroll
    for (int it = 0; it < 2; ++it) {
      int r = pr + 64 * it;
      int sw = (r & 7) << 4;
      float4 v = zpre[it];
      unsigned int p0 = packbf(v.x), p1 = packbf(v.y),
                   p2 = packbf(v.z), p3 = packbf(v.w);
      *reinterpret_cast<ushort4*>(Ab + r * 128 + ((8 * pq) ^ sw)) =
          make_ushort4((ushort)(p0 >> 16), (ushort)(p1 >> 16),
                       (ushort)(p2 >> 16), (ushort)(p3 >> 16));
      *reinterpret_cast<ushort4*>(Ab + r * 128 + ((64 + 8 * pq) ^ sw)) =
          make_ushort4((ushort)(p0 & 0xffff), (ushort)(p1 & 0xffff),
                       (ushort)(p2 & 0xffff), (ushort)(p3 & 0xffff));
    }
    // ---- B: load H in-phase (L2-hot), split, swizzled LDS write
#pragma unroll
    for (int it = 0; it < 4; ++it) {
      int r = pr + 64 * it;
      uint4 h = (r < 255) ? *reinterpret_cast<const uint4*>(
                                Hpack + r * NTOP + kb + 4 * pq)
                          : make_uint4(0u, 0u, 0u, 0u);
      int sw = (r & 7) << 4;
      *reinterpret_cast<ushort4*>(Bb + r * 128 + ((8 * pq) ^ sw)) =
          make_ushort4((ushort)(h.x >> 16), (ushort)(h.y >> 16),
                       (ushort)(h.z >> 16), (ushort)(h.w >> 16));
      *reinterpret_cast<ushort4*>(Bb + r * 128 + ((64 + 8 * pq) ^ sw)) =
          make_ushort4((ushort)(h.x & 0xffff), (ushort)(h.y & 0xffff),
                       (ushort)(h.z & 0xffff), (ushort)(h.w & 0xffff));
    }
    // ---- prefetch next z chunk (overlaps barrier + MFMA phase)
    if (kc < 7) {
#pragma unroll
      for (int it = 0; it < 2; ++it) {
        int r = pr + 64 * it;
        zpre[it] = *reinterpret_cast<const float4*>(
            z + (row0 + r) * NTOP + kb + 32 + 4 * pq);
      }
    }
    __syncthreads();                  // staged
    // ---- fragments + 48 MFMA (one K=32 step, bf16x3)
    bf16x8 ah[4], al[4];
#pragma unroll
    for (int mt = 0; mt < 4; ++mt) {
      int r = 64 * wr + 16 * mt + l15;
      int sw = (r & 7) << 4;
      ah[mt] = *reinterpret_cast<const bf16x8*>(Ab + r * 128 + ((16 * l4) ^ sw));
      al[mt] = *reinterpret_cast<const bf16x8*>(
          Ab + r * 128 + ((64 + 16 * l4) ^ sw));
    }
#pragma unroll
    for (int nt = 0; nt < 4; ++nt) {
      int n = 64 * wc + 16 * nt + l15;
      int sw = (n & 7) << 4;
      bf16x8 bh = *reinterpret_cast<const bf16x8*>(
          Bb + n * 128 + ((16 * l4) ^ sw));
      bf16x8 bl = *reinterpret_cast<const bf16x8*>(
          Bb + n * 128 + ((64 + 16 * l4) ^ sw));
#pragma unroll
      for (int mt = 0; mt < 4; ++mt) {
        acc[mt][nt] = __builtin_amdgcn_mfma_f32_16x16x32_bf16(
            ah[mt], bh, acc[mt][nt], 0, 0, 0);
        acc[mt][nt] = __builtin_amdgcn_mfma_f32_16x16x32_bf16(
            ah[mt], bl, acc[mt][nt], 0, 0, 0);
        acc[mt][nt] = __builtin_amdgcn_mfma_f32_16x16x32_bf16(
            al[mt], bh, acc[mt][nt], 0, 0, 0);
      }
    }
  }

  // ---- epilogue pass A: zc, sp=softplus, in-register prefix scan
  // C layout: row = 64wr+16mt+4*l4+i, col = 64wc+16nt+l15
  float lt[4];
#pragma unroll
  for (int nt = 0; nt < 4; ++nt) {
    int col = 64 * wc + 16 * nt + l15;
    lt[nt] = (col < 255) ? __logf((float)(255 - col)) : 0.f;
  }
#pragma unroll
  for (int mt = 0; mt < 4; ++mt)
#pragma unroll
    for (int i = 0; i < 4; ++i) {
      float carry = 0.f;
#pragma unroll
      for (int nt = 0; nt < 4; ++nt) {
        float a = acc[mt][nt][i];
        float t1 = __expf(-a);
        float s1 = __builtin_amdgcn_rcpf(1.f + t1);   // sigmoid(logit)
        float x = s1 - lt[nt];
        float t = __expf(-x);
        float zc = __builtin_amdgcn_rcpf(1.f + t);    // sigmoid(x)
        float sp = x + __logf(1.f + t);               // softplus(x)
        if ((wc == 3) && (nt == 3) && (l15 == 15)) {  // col 255 dummy
          zc = 1.f; sp = 0.f;
        }
        float incl = scan16(sp);
        float Sl = carry + (incl - sp);               // exclusive prefix
        acc[mt][nt][i] = zc * __expf(-Sl);
        carry += __shfl(incl, 15, 16);
      }
      if (l15 == 0)
        rowT[(64 * wr + 16 * mt + 4 * l4 + i) * 5 + wc] = carry;
    }
  __syncthreads();

  // ---- pass B: cross-wave offset + direct global store
#pragma unroll
  for (int mt = 0; mt < 4; ++mt)
#pragma unroll
    for (int i = 0; i < 4; ++i) {
      int r = 64 * wr + 16 * mt + 4 * l4 + i;
      float ew = 1.f;
      if (wc > 0) {
        float W = rowT[r * 5 + 0];
        if (wc > 1) W += rowT[r * 5 + 1];
        if (wc > 2) W += rowT[r * 5 + 2];
        ew = __expf(-W);
      }
      float* op = out + (row0 + r) * NTOP + 64 * wc + l15;
#pragma unroll
      for (int nt = 0; nt < 4; ++nt) op[16 * nt] = acc[mt][nt][i] * ew;
    }
}

// ---------------------------------------------------------------- launch
extern "C" void kernel_launch(void* const* d_in, const int* in_sizes, int n_in,
                              void* d_out, int out_size, void* d_ws, size_t ws_size,
                              hipStream_t stream) {
  const float* z   = (const float*)d_in[0];
  const float* h0  = (const float*)d_in[1];
  const float* Wih = (const float*)d_in[2];
  const float* Whh = (const float*)d_in[3];
  const float* bih = (const float*)d_in[4];
  const float* bhh = (const float*)d_in[5];
  float* out = (float*)d_out;
  unsigned int* Hpack = (unsigned int*)d_ws;  // 255*256 uint32

  rsbc_recur<<<1, 512, 0, stream>>>(Wih, Whh, bih, bhh, h0, Hpack);
  const int nrows = out_size / NTOP;          // 131072
  const int blocks = nrows / 128;             // 1024
  rsbc_gemm_sb<<<blocks, 512, 0, stream>>>(z, Hpack, out);
}